// Round 18
// baseline (135.275 us; speedup 1.0000x reference)
//
#include <hip/hip_runtime.h>
#include <hip/hip_bf16.h>

// Head: x(8,2048,1024) fp32 @ {Wq,Wk,Wv}(1024,128) fp32
//   -> causal softmax((QK^T)/32) @ V -> out FP32.
// Ledger: best 133.7us (R25) = 2-phase qkv (41us) + QBLK32 attn K-dbuf.
// qkv pinned at ~41us across SIX staging/prefetch/layout variants -> the
// invariant costs are B-L2 (393MB) + phase serialization at 16 waves/CU.
// R26: M=64 rows/block on the PROVEN 2-phase structure (R8's M=64 try was
// confounded by a serial pipeline + bad LDS layout): grid 256 (1 block/CU),
// 128KB static frag-linear LDS (guide's 8-phase template uses 128KiB
// static), acc[4][3], R8's correctness-verified M=64 epilogue. B-L2
// traffic halves to 196MB. Model: ~45K cyc/CU ~= 19us, worst-case skew
// ~29us < 41. attn/prep frozen.

typedef __attribute__((ext_vector_type(8))) short bf16x8;   // 8 bf16 = 4 VGPRs
typedef __attribute__((ext_vector_type(4))) float f32x4;    // MFMA C/D frag

#define NB   8
#define TT   2048
#define CDIM 1024
#define HD   128
#define NTOK (NB * TT)   // 16384
#define NW   384

using bf16 = __hip_bfloat16;

__device__ __forceinline__ short f2bs(float f) {          // RNE bf16
    unsigned u = __builtin_bit_cast(unsigned, f);
    return (short)((u + 0x7FFF + ((u >> 16) & 1)) >> 16);
}

// ---------- prep: pack W into MFMA B-fragment order ----------
__global__ __launch_bounds__(256) void prep_w_kernel(
        const float* __restrict__ Wq, const float* __restrict__ Wk,
        const float* __restrict__ Wv, bf16* __restrict__ Wp) {
    const int f  = blockIdx.x * 256 + threadIdx.x;        // 0..49151
    const int l  = f & 63;
    const int nt = (f >> 6) % 24;
    const int sl = f / 1536;
    const int ln = l & 15, quad = l >> 4;
    const int n  = nt * 16 + ln;                          // 0..383
    const int w  = n >> 7, h = n & 127;
    const float* W = (w == 0) ? Wq : (w == 1) ? Wk : Wv;
    const int k0 = sl * 32 + quad * 8;
    bf16x8 frag;
    #pragma unroll
    for (int j = 0; j < 8; j++)
        frag[j] = f2bs(W[(long)(k0 + j) * HD + h]);
    *(bf16x8*)((short*)Wp + (long)f * 8) = frag;          // coalesced 16B/thread
}

// ---------- QKV projection: grid 256 (64 rows/block), block 512 ----------
// wave w: cols [48w,48w+48). Phase 1: x -> bf16 A-frags in LDS
// (frag-linear, 128KB). Phase 2: 32-slice MFMA, acc[4][3], B prefetch.
// Epilogue: Q -> global; K,V -> kT/vT transpose -> 2 packed Kp/Vp tiles.
__global__ __launch_bounds__(512, 2) void qkv_proj_kernel(
        const float* __restrict__ x, const bf16* __restrict__ Wp,
        bf16* __restrict__ Q, bf16* __restrict__ Kp, bf16* __restrict__ Vp) {
    __shared__ __align__(16) short aLDS[64 * 1024];         // 128KB A-frags
    const int tid  = threadIdx.x;
    const int wave = tid >> 6, lane = tid & 63;
    const int quad = lane >> 4, ln = lane & 15;
    const long mbase = (long)blockIdx.x * 64;

    // ----- phase 1: x -> bf16 frags in LDS (16 frags/thread) -----
    // fid = fmt*2048 + fsl*64 + fl ; src row = mbase + fmt*16 + (fl&15),
    // col = fsl*32 + (fl>>4)*8 ; dst byte = fid*16 (frag-linear).
    #pragma unroll
    for (int j = 0; j < 16; j++) {
        const int fid = j * 512 + tid;                    // 0..8191
        const int fl  = fid & 63;
        const int fsl = (fid >> 6) & 31;
        const int fmt = fid >> 11;                        // 0..3
        const float4* src = (const float4*)(
            x + (mbase + fmt * 16 + (fl & 15)) * CDIM + fsl * 32 + (fl >> 4) * 8);
        float4 u = src[0], v = src[1];
        bf16x8 fr;
        fr[0] = f2bs(u.x); fr[1] = f2bs(u.y); fr[2] = f2bs(u.z); fr[3] = f2bs(u.w);
        fr[4] = f2bs(v.x); fr[5] = f2bs(v.y); fr[6] = f2bs(v.z); fr[7] = f2bs(v.w);
        *(bf16x8*)(aLDS + (long)fid * 8) = fr;            // linear: no conflicts
    }
    __syncthreads();

    // ----- phase 2: MFMA main loop over 32 k-slices (B prefetch) -----
    const f32x4 zero = {0.f, 0.f, 0.f, 0.f};
    f32x4 acc[4][3];
    #pragma unroll
    for (int mt = 0; mt < 4; mt++)
        #pragma unroll
        for (int nt = 0; nt < 3; nt++) acc[mt][nt] = zero;

    const short* a0 = aLDS + lane * 8;         // + mt*16384 + sl*512
    const short* bp = (const short*)Wp + (long)wave * 1536 + lane * 8;

    bf16x8 b0 = *(const bf16x8*)(bp);
    bf16x8 b1 = *(const bf16x8*)(bp + 512);
    bf16x8 b2 = *(const bf16x8*)(bp + 1024);

    #pragma unroll 4
    for (int sl = 0; sl < 32; sl++) {
        bf16x8 cb0 = b0, cb1 = b1, cb2 = b2;
        if (sl + 1 < 32) {                                // prefetch next slice
            b0 = *(const bf16x8*)(bp + (long)(sl + 1) * 12288);
            b1 = *(const bf16x8*)(bp + (long)(sl + 1) * 12288 + 512);
            b2 = *(const bf16x8*)(bp + (long)(sl + 1) * 12288 + 1024);
        }
        #pragma unroll
        for (int mt = 0; mt < 4; mt++) {
            bf16x8 af = *(const bf16x8*)(a0 + mt * 16384 + sl * 512);
            acc[mt][0] = __builtin_amdgcn_mfma_f32_16x16x32_bf16(af, cb0, acc[mt][0], 0, 0, 0);
            acc[mt][1] = __builtin_amdgcn_mfma_f32_16x16x32_bf16(af, cb1, acc[mt][1], 0, 0, 0);
            acc[mt][2] = __builtin_amdgcn_mfma_f32_16x16x32_bf16(af, cb2, acc[mt][2], 0, 0, 0);
        }
    }

    // ----- epilogue (R8-verified M=64): Q -> global; K,V -> packed tiles ---
    __syncthreads();                                      // aLDS dead
    short* kT = aLDS;                                     // [64][136] = 8704 sh
    short* vT = aLDS + 8704;                              // [128][72] = 9216 sh

    #pragma unroll
    for (int mt = 0; mt < 4; mt++) {
        #pragma unroll
        for (int nt = 0; nt < 3; nt++) {
            const int n = wave * 48 + nt * 16 + ln;
            #pragma unroll
            for (int r = 0; r < 4; r++) {
                const int row = mt * 16 + quad * 4 + r;   // local token 0..63
                const short hv = f2bs(acc[mt][nt][r]);
                if (n < 128) {
                    long g = mbase + row;
                    int b = (int)(g >> 11), t = (int)(g & (TT - 1));
                    Q[((long)b * TT + t) * HD + n] = __builtin_bit_cast(bf16, hv);
                } else if (n < 256) {
                    kT[row * 136 + (n - 128)] = hv;       // K[tok][h]
                } else {
                    vT[(n - 256) * 72 + row] = hv;        // V^T[h][tok]
                }
            }
        }
    }
    __syncthreads();

    // packed frag writes: wave w emits K frag w and V frag w for both tiles
    #pragma unroll
    for (int tt = 0; tt < 2; tt++) {
        const long tile = (long)blockIdx.x * 2 + tt;      // = b*64 + jt
        const int  kc = wave >> 1, ntk = wave & 1;
        bf16x8 kv = *(const bf16x8*)&kT[(tt*32 + ntk*16 + ln)*136 + kc*32 + quad*8];
        *(bf16x8*)((short*)Kp + (tile*8 + wave)*512 + lane*8) = kv;
        bf16x8 vv = *(const bf16x8*)&vT[(wave*16 + ln)*72 + tt*32 + quad*8];
        *(bf16x8*)((short*)Vp + (tile*8 + wave)*512 + lane*8) = vv;
    }
}

// ---------- causal flash attention (QBLK=32, K double-buffered) ----------
// Frozen R13 winner. Static-max softmax; grid 512, block 256 = 4 waves;
// waves split the key range, partials tree-reduced in LDS (4 -> 2 -> 1).
#define ATTN_TILE32(CUR, NXT)                                                    \
  {                                                                              \
    const int j0 = kt * 32;                                                      \
    const short* vbase = Vpb + (long)kt * 4096 + lane * 8;                       \
    bf16x8 vf[8];                                                                \
    _Pragma("unroll")                                                            \
    for (int ht = 0; ht < 8; ht++)                                               \
        vf[ht] = *(const bf16x8*)(vbase + ht*512);                               \
    if (kt + 1 < t1) {                                                           \
        const short* nkb = Kpb + (long)(kt + 1) * 4096 + lane * 8;               \
        _Pragma("unroll")                                                        \
        for (int kc = 0; kc < 4; kc++)                                           \
            _Pragma("unroll")                                                    \
            for (int ntk = 0; ntk < 2; ntk++)                                    \
                NXT[kc][ntk] = *(const bf16x8*)(nkb + (kc*2 + ntk)*512);         \
    }                                                                            \
    f32x4 s[2][2];                                                               \
    s[0][0] = zero; s[0][1] = zero; s[1][0] = zero; s[1][1] = zero;              \
    _Pragma("unroll")                                                            \
    for (int kc = 0; kc < 4; kc++)                                               \
        _Pragma("unroll")                                                        \
        for (int mt = 0; mt < 2; mt++) {                                         \
            s[mt][0] = __builtin_amdgcn_mfma_f32_16x16x32_bf16(qf[mt][kc], CUR[kc][0], s[mt][0], 0, 0, 0); \
            s[mt][1] = __builtin_amdgcn_mfma_f32_16x16x32_bf16(qf[mt][kc], CUR[kc][1], s[mt][1], 0, 0, 0); \
        }                                                                        \
    short* pb = pwave + (kt & 1) * 1280;                                         \
    _Pragma("unroll")                                                            \
    for (int mt = 0; mt < 2; mt++)                                               \
        _Pragma("unroll")                                                        \
        for (int r = 0; r < 4; r++) {                                            \
            const int q = qb + mt*16 + quad*4 + r;                               \
            _Pragma("unroll")                                                    \
            for (int ntk = 0; ntk < 2; ntk++) {                                  \
                float p = __expf(s[mt][ntk][r] * 0.03125f);                      \
                if (j0 + ntk*16 + ln > q) p = 0.f;                               \
                li[mt][r] += p;                                                  \
                pb[(mt*16 + quad*4 + r)*40 + ntk*16 + ln] = f2bs(p);             \
            }                                                                    \
        }                                                                        \
    bf16x8 pf[2];                                                                \
    _Pragma("unroll")                                                            \
    for (int mt = 0; mt < 2; mt++)                                               \
        pf[mt] = *(const bf16x8*)&pb[(mt*16 + ln)*40 + quad*8];                  \
    _Pragma("unroll")                                                            \
    for (int mt = 0; mt < 2; mt++)                                               \
        _Pragma("unroll")                                                        \
        for (int ht = 0; ht < 8; ht++)                                           \
            o[mt][ht] = __builtin_amdgcn_mfma_f32_16x16x32_bf16(pf[mt], vf[ht], o[mt][ht], 0, 0, 0); \
    kt++;                                                                        \
  }

__global__ __launch_bounds__(256, 2) void attn_kernel(
        const bf16* __restrict__ Q, const bf16* __restrict__ Kp,
        const bf16* __restrict__ Vp, float* __restrict__ out) {
    // union: pbuf (4 waves x 2 x [32][40] shorts = 20480B, live in loop)
    //        red [2][32][128] f32 = 32768B + redl [2][32] f32 = 256B, after
    __shared__ __align__(16) char smem[33024];

    const int tid  = threadIdx.x;
    const int wave = tid >> 6, lane = tid & 63;
    const int quad = lane >> 4, ln = lane & 15;
    // block -> (b, qi): balanced pairing {63-r, r}
    const int b   = blockIdx.x & 7;
    const int idx = blockIdx.x >> 3;           // 0..63
    const int qi  = (idx >> 5) ? (idx & 31) : 63 - (idx & 31);
    const int qb  = qi * 32;
    const int ntiles = qi + 1;                 // key tiles of 32
    const int t0 = (ntiles * wave) >> 2;
    const int t1 = (ntiles * (wave + 1)) >> 2;

    const bf16*  Qb  = Q + (long)b * TT * HD;
    const short* Kpb = (const short*)Kp + (long)b * 64 * 4096;  // 4096 sh/tile
    const short* Vpb = (const short*)Vp + (long)b * 64 * 4096;

    short* pwave = (short*)smem + wave * 2560;             // 2 x [32][40]

    bf16x8 qf[2][4];
    #pragma unroll
    for (int mt = 0; mt < 2; mt++)
        #pragma unroll
        for (int kc = 0; kc < 4; kc++)
            qf[mt][kc] = *(const bf16x8*)(Qb + (long)(qb + mt*16 + ln)*HD + kc*32 + quad*8);

    const f32x4 zero = {0.f, 0.f, 0.f, 0.f};
    f32x4 o[2][8];
    #pragma unroll
    for (int mt = 0; mt < 2; mt++)
        #pragma unroll
        for (int ht = 0; ht < 8; ht++) o[mt][ht] = zero;
    float li[2][4] = {{0.f,0.f,0.f,0.f},{0.f,0.f,0.f,0.f}};

    bf16x8 kfA[4][2], kfB[4][2];
    if (t0 < t1) {
        const short* kb0 = Kpb + (long)t0 * 4096 + lane * 8;
        #pragma unroll
        for (int kc = 0; kc < 4; kc++)
            #pragma unroll
            for (int ntk = 0; ntk < 2; ntk++)
                kfA[kc][ntk] = *(const bf16x8*)(kb0 + (kc*2 + ntk)*512);
    }
    int kt = t0;
    while (kt < t1) {
        ATTN_TILE32(kfA, kfB)
        if (kt >= t1) break;
        ATTN_TILE32(kfB, kfA)
    }

    // reduce li across the 16 lanes sharing each row
    #pragma unroll
    for (int mt = 0; mt < 2; mt++)
        #pragma unroll
        for (int r = 0; r < 4; r++)
            #pragma unroll
            for (int d = 1; d < 16; d <<= 1) li[mt][r] += __shfl_xor(li[mt][r], d);

    // ---- 4 -> 2 -> 1 tree reduce in LDS (pbuf dead now) ----
    __syncthreads();
    float* red  = (float*)smem;                 // [2][32][128]
    float* redl = (float*)(smem + 32768);       // [2][32]
    if (wave & 1) {                             // waves 1,3 -> slot wave>>1
        const int slot = wave >> 1;
        #pragma unroll
        for (int mt = 0; mt < 2; mt++)
            #pragma unroll
            for (int ht = 0; ht < 8; ht++)
                #pragma unroll
                for (int r = 0; r < 4; r++)
                    red[slot*4096 + (mt*16 + quad*4 + r)*128 + ht*16 + ln] = o[mt][ht][r];
        if (ln == 0)
            #pragma unroll
            for (int mt = 0; mt < 2; mt++)
                #pragma unroll
                for (int r = 0; r < 4; r++)
                    redl[slot*32 + mt*16 + quad*4 + r] = li[mt][r];
    }
    __syncthreads();
    if (!(wave & 1)) {                          // waves 0,2 absorb
        const int slot = wave >> 1;
        #pragma unroll
        for (int mt = 0; mt < 2; mt++) {
            #pragma unroll
            for (int ht = 0; ht < 8; ht++)
                #pragma unroll
                for (int r = 0; r < 4; r++)
                    o[mt][ht][r] += red[slot*4096 + (mt*16 + quad*4 + r)*128 + ht*16 + ln];
            #pragma unroll
            for (int r = 0; r < 4; r++)
                li[mt][r] += redl[slot*32 + mt*16 + quad*4 + r];
        }
    }
    __syncthreads();
    if (wave == 2) {                            // wave 2 -> slot 0
        #pragma unroll
        for (int mt = 0; mt < 2; mt++) {
            #pragma unroll
            for (int ht = 0; ht < 8; ht++)
                #pragma unroll
                for (int r = 0; r < 4; r++)
                    red[(mt*16 + quad*4 + r)*128 + ht*16 + ln] = o[mt][ht][r];
            if (ln == 0)
                #pragma unroll
                for (int r = 0; r < 4; r++)
                    redl[mt*16 + quad*4 + r] = li[mt][r];
        }
    }
    __syncthreads();
    if (wave == 0) {                            // final combine + store
        #pragma unroll
        for (int mt = 0; mt < 2; mt++) {
            #pragma unroll
            for (int r = 0; r < 4; r++)
                li[mt][r] += redl[mt*16 + quad*4 + r];
            #pragma unroll
            for (int ht = 0; ht < 8; ht++)
                #pragma unroll
                for (int r = 0; r < 4; r++) {
                    float v = o[mt][ht][r] + red[(mt*16 + quad*4 + r)*128 + ht*16 + ln];
                    out[((long)b*TT + qb + mt*16 + quad*4 + r)*HD + ht*16 + ln] = v / li[mt][r];
                }
        }
    }
}

extern "C" void kernel_launch(void* const* d_in, const int* in_sizes, int n_in,
                              void* d_out, int out_size, void* d_ws, size_t ws_size,
                              hipStream_t stream) {
    const float* x  = (const float*)d_in[0];
    const float* Wq = (const float*)d_in[1];
    const float* Wk = (const float*)d_in[2];
    const float* Wv = (const float*)d_in[3];
    float* outp = (float*)d_out;

    // ws: Wp 768KB | Q 4MB | Kp 4MB | Vp 4MB  ~= 12.75MB
    bf16* Wp = (bf16*)d_ws;
    bf16* Qm = Wp + (long)NW * CDIM;
    bf16* Kp = Qm + (long)NTOK * HD;
    bf16* Vp = Kp + (long)NTOK * HD;

    prep_w_kernel<<<192, 256, 0, stream>>>(Wq, Wk, Wv, Wp);
    qkv_proj_kernel<<<256, 512, 0, stream>>>(x, Wp, Qm, Kp, Vp);
    attn_kernel<<<NB * 64, 256, 0, stream>>>(Qm, Kp, Vp, outp);
}